// Round 7
// baseline (202.435 us; speedup 1.0000x reference)
//
#include <hip/hip_runtime.h>
#include <stdint.h>

// Dyna_Dec: out[b,d,l] = sum_c x[b,c,l] * w[l,c,d] + bias[l,d]
// B=128, C=32, L=4096, fp32 in/out.
//
// R6 post-mortem: 88us with VALUBusy 12.7%, hbm 16%, occ 25%, traffic
// compulsory -> latency-serialized (VGPR=52: compiler kept no loads in
// flight; per-lane W row gather = 64-line scatter per load, hostile to
// pipelining). Fix: W staged through LDS with COALESCED block copies
// (W[l,c0:c0+4,:] is 512B contiguous per l), compute reads ds_read_b128
// from padded rows (132 floats: bank stride 4 -> dense, conflict-free),
// x loads explicitly double-buffered so waits are vmcnt(N>0).
//
// Block 256 = 64 l-lanes x 4 d-octet waves; acc[8 b][8 d]; grid 64 x 16;
// LDS 33.8KB -> 4 blocks/CU (16 waves). Stores nontemporal (write-once).

namespace {

constexpr int kC = 32;
constexpr int kL = 4096;
constexpr int kNB = 8;       // batches per block/thread
constexpr int kND = 8;       // d per thread
constexpr int kCChunk = 4;   // c's staged per LDS round
constexpr int kRowPad = kCChunk * 32 + 4;  // 132 floats: 16B-aligned rows, dense b128 reads

__global__ __launch_bounds__(256, 4)
void dyna_dec(const float* __restrict__ x,
              const float* __restrict__ w,
              const float* __restrict__ bias,
              float* __restrict__ out) {
    __shared__ float sw[64 * kRowPad];  // 33792 B

    const int t  = threadIdx.x;
    const int lt = t & 63;
    const int dg = t >> 6;
    const int lc = blockIdx.x * 64;       // l-chunk base
    const int l  = lc + lt;
    const int b0 = blockIdx.y * kNB;      // gridDim.y = 128/8 = 16
    const int d0 = dg * kND;

    float acc[kNB][kND];
#pragma unroll
    for (int i = 0; i < kNB; ++i)
#pragma unroll
        for (int j = 0; j < kND; ++j) acc[i][j] = 0.0f;

    const float* xp = x + (size_t)b0 * (kC * kL) + l;  // + i*C*L + c*L

    // x double-buffer: preload c=0
    float xr[2][kNB];
#pragma unroll
    for (int i = 0; i < kNB; ++i)
        xr[0][i] = xp[(size_t)i * (kC * kL)];

    for (int k = 0; k < kC / kCChunk; ++k) {
        // ---- stage W[lc..lc+63, 4k..4k+3, 0..31] -> LDS (coalesced) ----
        // global: per l-row 512B contiguous at w + (l*32 + 4k)*32
        const float* wsrc = w + ((size_t)lc * kC + k * kCChunk) * 32;
#pragma unroll
        for (int h = 0; h < 2; ++h) {
            float4 tmp[4];
#pragma unroll
            for (int i = 0; i < 4; ++i) {
                const int f4 = (h * 4 + i) * 256 + t;   // float4 index 0..2047
                const int lr = f4 >> 5;                  // l within chunk
                const int m  = f4 & 31;                  // float4 within 512B row
                tmp[i] = *reinterpret_cast<const float4*>(
                    wsrc + (size_t)lr * (kC * 32) + m * 4);
            }
#pragma unroll
            for (int i = 0; i < 4; ++i) {
                const int f4 = (h * 4 + i) * 256 + t;
                const int lr = f4 >> 5;
                const int m  = f4 & 31;
                *reinterpret_cast<float4*>(&sw[lr * kRowPad + m * 4]) = tmp[i];
            }
        }
        __syncthreads();

#pragma unroll
        for (int cc = 0; cc < kCChunk; ++cc) {
            const int c = k * kCChunk + cc;
            // prefetch x for c+1 (kept in flight across the FMA block)
            if (c + 1 < kC) {
#pragma unroll
                for (int i = 0; i < kNB; ++i)
                    xr[(c + 1) & 1][i] =
                        xp[(size_t)i * (kC * kL) + (size_t)(c + 1) * kL];
            }
            // W[l, c, d0..d0+7] from LDS: 2 x ds_read_b128, dense banks
            const float4 wa = *reinterpret_cast<const float4*>(
                &sw[lt * kRowPad + cc * 32 + d0]);
            const float4 wb = *reinterpret_cast<const float4*>(
                &sw[lt * kRowPad + cc * 32 + d0 + 4]);
            const float ws[kND] = {wa.x, wa.y, wa.z, wa.w,
                                   wb.x, wb.y, wb.z, wb.w};
#pragma unroll
            for (int i = 0; i < kNB; ++i)
#pragma unroll
                for (int j = 0; j < kND; ++j)
                    acc[i][j] += xr[c & 1][i] * ws[j];
        }
        __syncthreads();  // protect LDS before next stage
    }

    // bias[l, d0..d0+7] (one-time 2x float4 gather)
    const float4 bv0 = *reinterpret_cast<const float4*>(bias + (size_t)l * kC + d0);
    const float4 bv1 = *reinterpret_cast<const float4*>(bias + (size_t)l * kC + d0 + 4);
    const float bb[kND] = {bv0.x, bv0.y, bv0.z, bv0.w,
                           bv1.x, bv1.y, bv1.z, bv1.w};

#pragma unroll
    for (int i = 0; i < kNB; ++i) {
        float* op = out + ((size_t)(b0 + i) * kC + d0) * kL + l;
#pragma unroll
        for (int j = 0; j < kND; ++j)
            __builtin_nontemporal_store(acc[i][j] + bb[j], op + (size_t)j * kL);
    }
}

}  // namespace

extern "C" void kernel_launch(void* const* d_in, const int* in_sizes, int n_in,
                              void* d_out, int out_size, void* d_ws, size_t ws_size,
                              hipStream_t stream) {
    // inputs: 0=x (B,C,H,W) fp32, 1=px (unused), 2=weight (L*C, C) fp32,
    //         3=bias (L*C) fp32
    const float* x    = (const float*)d_in[0];
    const float* wgt  = (const float*)d_in[2];
    const float* bias = (const float*)d_in[3];
    float* out = (float*)d_out;

    dim3 grid(kL / 64, 128 / kNB);  // 64 x 16 = 1024 blocks
    dim3 block(256);
    hipLaunchKernelGGL(dyna_dec, grid, block, 0, stream, x, wgt, bias, out);
}